// Round 2
// baseline (1463.810 us; speedup 1.0000x reference)
//
#include <hip/hip_runtime.h>
#include <math.h>

#define B_  4
#define S_  2048
#define H_  768
#define NH_ 12
#define HD_ 64
#define M_  (B_*S_)   // 8192

// ---------------------------------------------------------------------------
// GEMM: C[m][n] = sum_k A[m][k] * W[n][k] + bias[n] (+ res[m][n] if ADD_RES)
// 64x64 tile, BK=16, 256 threads (16x16), 4x4 per thread.
// ---------------------------------------------------------------------------
template<bool ADD_RES>
__global__ __launch_bounds__(256)
void gemm_bias(const float* __restrict__ A, const float* __restrict__ W,
               const float* __restrict__ bias, const float* __restrict__ res,
               float* __restrict__ C, int Mdim, int Ndim, int Kdim) {
    __shared__ __align__(16) float As[16][64];
    __shared__ __align__(16) float Ws[16][64];
    const int tid = threadIdx.x;
    const int tx = tid & 15, ty = tid >> 4;
    const int m0 = blockIdx.x * 64, n0 = blockIdx.y * 64;
    const int lr  = tid & 63;          // row within tile for staging
    const int lk4 = (tid >> 6) * 4;    // k sub-offset {0,4,8,12}

    float acc[4][4] = {};

    for (int k0 = 0; k0 < Kdim; k0 += 16) {
        float4 av = *(const float4*)(A + (size_t)(m0 + lr) * Kdim + k0 + lk4);
        float4 wv = *(const float4*)(W + (size_t)(n0 + lr) * Kdim + k0 + lk4);
        __syncthreads();   // previous iteration done reading LDS
        As[lk4+0][lr] = av.x; As[lk4+1][lr] = av.y;
        As[lk4+2][lr] = av.z; As[lk4+3][lr] = av.w;
        Ws[lk4+0][lr] = wv.x; Ws[lk4+1][lr] = wv.y;
        Ws[lk4+2][lr] = wv.z; Ws[lk4+3][lr] = wv.w;
        __syncthreads();
        #pragma unroll
        for (int kk = 0; kk < 16; kk++) {
            float4 a = *(const float4*)&As[kk][ty * 4];
            float4 b = *(const float4*)&Ws[kk][tx * 4];
            acc[0][0] += a.x*b.x; acc[0][1] += a.x*b.y; acc[0][2] += a.x*b.z; acc[0][3] += a.x*b.w;
            acc[1][0] += a.y*b.x; acc[1][1] += a.y*b.y; acc[1][2] += a.y*b.z; acc[1][3] += a.y*b.w;
            acc[2][0] += a.z*b.x; acc[2][1] += a.z*b.y; acc[2][2] += a.z*b.z; acc[2][3] += a.z*b.w;
            acc[3][0] += a.w*b.x; acc[3][1] += a.w*b.y; acc[3][2] += a.w*b.z; acc[3][3] += a.w*b.w;
        }
    }

    const int cn = n0 + tx * 4;
    float4 bv = *(const float4*)(bias + cn);
    #pragma unroll
    for (int i = 0; i < 4; i++) {
        const int cm = m0 + ty * 4 + i;
        float4 o;
        o.x = acc[i][0] + bv.x; o.y = acc[i][1] + bv.y;
        o.z = acc[i][2] + bv.z; o.w = acc[i][3] + bv.w;
        if (ADD_RES) {
            float4 r = *(const float4*)(res + (size_t)cm * Ndim + cn);
            o.x += r.x; o.y += r.y; o.z += r.z; o.w += r.w;
        }
        *(float4*)(C + (size_t)cm * Ndim + cn) = o;
    }
}

// ---------------------------------------------------------------------------
// Flash attention: one block per (64-query tile, head, batch).
// Q,K LDS tiles d-major; V row-major (padded); P row-major (padded).
// Staging: 64x64 tile = 4096 floats = 256 thr x 16 floats (4x float4 each).
// ---------------------------------------------------------------------------
__global__ __launch_bounds__(256)
void flash_attn(const float* __restrict__ q, const float* __restrict__ k,
                const float* __restrict__ v, const float* __restrict__ mask,
                float* __restrict__ ctx) {
    const int qt = blockIdx.x, h = blockIdx.y, b = blockIdx.z;
    __shared__ __align__(16) float Qs[64][64];   // [d][r]
    __shared__ __align__(16) float Ks[64][64];   // [d][c]
    __shared__ __align__(16) float Vs[64][68];   // [c][d]  (pad 4)
    __shared__ __align__(16) float Ps[64][68];   // [r][c]  (pad 4)

    const int tid = threadIdx.x;
    const int tx = tid & 15, ty = tid >> 4;
    const int sr = tid >> 2;          // staging row 0..63
    const int sd = (tid & 3) * 16;    // staging d-offset {0,16,32,48}

    // stage Q tile transposed: Qs[d][r] (full 64 d-values)
    {
        const float* qp = q + ((size_t)(b * S_ + qt * 64 + sr)) * H_ + h * HD_ + sd;
        #pragma unroll
        for (int u = 0; u < 4; u++) {
            float4 qv = *(const float4*)(qp + u * 4);
            Qs[sd + u*4 + 0][sr] = qv.x; Qs[sd + u*4 + 1][sr] = qv.y;
            Qs[sd + u*4 + 2][sr] = qv.z; Qs[sd + u*4 + 3][sr] = qv.w;
        }
    }

    float m_r[4], l_r[4], o_acc[4][4];
    #pragma unroll
    for (int i = 0; i < 4; i++) {
        m_r[i] = -INFINITY; l_r[i] = 0.f;
        o_acc[i][0] = o_acc[i][1] = o_acc[i][2] = o_acc[i][3] = 0.f;
    }

    for (int c0 = 0; c0 < S_; c0 += 64) {
        const float* kp = k + ((size_t)(b * S_ + c0 + sr)) * H_ + h * HD_ + sd;
        const float* vp = v + ((size_t)(b * S_ + c0 + sr)) * H_ + h * HD_ + sd;
        float4 kv[4], vv[4];
        #pragma unroll
        for (int u = 0; u < 4; u++) { kv[u] = *(const float4*)(kp + u*4); vv[u] = *(const float4*)(vp + u*4); }
        __syncthreads();   // previous iteration done reading Ks/Vs (and Qs staged)
        #pragma unroll
        for (int u = 0; u < 4; u++) {
            Ks[sd + u*4 + 0][sr] = kv[u].x; Ks[sd + u*4 + 1][sr] = kv[u].y;
            Ks[sd + u*4 + 2][sr] = kv[u].z; Ks[sd + u*4 + 3][sr] = kv[u].w;
            *(float4*)&Vs[sr][sd + u*4] = vv[u];
        }
        __syncthreads();

        // S-tile: s[r][c] = sum_d Qs[d][r]*Ks[d][c]
        float sacc[4][4] = {};
        #pragma unroll 8
        for (int dd = 0; dd < 64; dd++) {
            float4 a = *(const float4*)&Qs[dd][ty * 4];
            float4 bb = *(const float4*)&Ks[dd][tx * 4];
            sacc[0][0] += a.x*bb.x; sacc[0][1] += a.x*bb.y; sacc[0][2] += a.x*bb.z; sacc[0][3] += a.x*bb.w;
            sacc[1][0] += a.y*bb.x; sacc[1][1] += a.y*bb.y; sacc[1][2] += a.y*bb.z; sacc[1][3] += a.y*bb.w;
            sacc[2][0] += a.z*bb.x; sacc[2][1] += a.z*bb.y; sacc[2][2] += a.z*bb.z; sacc[2][3] += a.z*bb.w;
            sacc[3][0] += a.w*bb.x; sacc[3][1] += a.w*bb.y; sacc[3][2] += a.w*bb.z; sacc[3][3] += a.w*bb.w;
        }

        // scale + additive mask (mask shape [B,1,1,S] -> per key column)
        float mk0 = mask[b * S_ + c0 + tx * 4 + 0];
        float mk1 = mask[b * S_ + c0 + tx * 4 + 1];
        float mk2 = mask[b * S_ + c0 + tx * 4 + 2];
        float mk3 = mask[b * S_ + c0 + tx * 4 + 3];
        #pragma unroll
        for (int i = 0; i < 4; i++) {
            sacc[i][0] = sacc[i][0] * 0.125f + mk0;
            sacc[i][1] = sacc[i][1] * 0.125f + mk1;
            sacc[i][2] = sacc[i][2] * 0.125f + mk2;
            sacc[i][3] = sacc[i][3] * 0.125f + mk3;
        }

        // online softmax update (row stats across the 16 tx lanes)
        float p[4][4];
        #pragma unroll
        for (int i = 0; i < 4; i++) {
            float rm = fmaxf(fmaxf(sacc[i][0], sacc[i][1]), fmaxf(sacc[i][2], sacc[i][3]));
            rm = fmaxf(rm, __shfl_xor(rm, 1));
            rm = fmaxf(rm, __shfl_xor(rm, 2));
            rm = fmaxf(rm, __shfl_xor(rm, 4));
            rm = fmaxf(rm, __shfl_xor(rm, 8));
            float mn = fmaxf(m_r[i], rm);
            float corr = __expf(m_r[i] - mn);
            p[i][0] = __expf(sacc[i][0] - mn);
            p[i][1] = __expf(sacc[i][1] - mn);
            p[i][2] = __expf(sacc[i][2] - mn);
            p[i][3] = __expf(sacc[i][3] - mn);
            float rs = p[i][0] + p[i][1] + p[i][2] + p[i][3];
            rs += __shfl_xor(rs, 1);
            rs += __shfl_xor(rs, 2);
            rs += __shfl_xor(rs, 4);
            rs += __shfl_xor(rs, 8);
            l_r[i] = l_r[i] * corr + rs;
            m_r[i] = mn;
            o_acc[i][0] *= corr; o_acc[i][1] *= corr;
            o_acc[i][2] *= corr; o_acc[i][3] *= corr;
            *(float4*)&Ps[ty * 4 + i][tx * 4] = *(float4*)&p[i][0];
        }
        __syncthreads();

        // O += P @ V
        #pragma unroll 8
        for (int cc = 0; cc < 64; cc++) {
            float4 vv4 = *(const float4*)&Vs[cc][tx * 4];
            float p0 = Ps[ty * 4 + 0][cc];
            float p1 = Ps[ty * 4 + 1][cc];
            float p2 = Ps[ty * 4 + 2][cc];
            float p3 = Ps[ty * 4 + 3][cc];
            o_acc[0][0] += p0*vv4.x; o_acc[0][1] += p0*vv4.y; o_acc[0][2] += p0*vv4.z; o_acc[0][3] += p0*vv4.w;
            o_acc[1][0] += p1*vv4.x; o_acc[1][1] += p1*vv4.y; o_acc[1][2] += p1*vv4.z; o_acc[1][3] += p1*vv4.w;
            o_acc[2][0] += p2*vv4.x; o_acc[2][1] += p2*vv4.y; o_acc[2][2] += p2*vv4.z; o_acc[2][3] += p2*vv4.w;
            o_acc[3][0] += p3*vv4.x; o_acc[3][1] += p3*vv4.y; o_acc[3][2] += p3*vv4.z; o_acc[3][3] += p3*vv4.w;
        }
        // loop-top __syncthreads protects Ks/Vs/Ps overwrite
    }

    #pragma unroll
    for (int i = 0; i < 4; i++) {
        const int r = qt * 64 + ty * 4 + i;
        float inv = 1.f / l_r[i];
        float4 o;
        o.x = o_acc[i][0] * inv; o.y = o_acc[i][1] * inv;
        o.z = o_acc[i][2] * inv; o.w = o_acc[i][3] * inv;
        *(float4*)(ctx + ((size_t)(b * S_ + r)) * H_ + h * HD_ + tx * 4) = o;
    }
}

// ---------------------------------------------------------------------------
// LayerNorm over last dim (768). One block (256 thr) per row, 3 elems/thread.
// ---------------------------------------------------------------------------
__global__ __launch_bounds__(256)
void layernorm_k(const float* __restrict__ hin, const float* __restrict__ g,
                 const float* __restrict__ beta, float* __restrict__ out) {
    const int row = blockIdx.x;
    const int tid = threadIdx.x;
    const float* x = hin + (size_t)row * H_;
    __shared__ float sm[4];

    float v0 = x[tid], v1 = x[tid + 256], v2 = x[tid + 512];
    float s = v0 + v1 + v2;
    #pragma unroll
    for (int o = 32; o > 0; o >>= 1) s += __shfl_xor(s, o);
    if ((tid & 63) == 0) sm[tid >> 6] = s;
    __syncthreads();
    float mu = (sm[0] + sm[1] + sm[2] + sm[3]) * (1.f / 768.f);

    float d0 = v0 - mu, d1 = v1 - mu, d2 = v2 - mu;
    float ss = d0*d0 + d1*d1 + d2*d2;
    #pragma unroll
    for (int o = 32; o > 0; o >>= 1) ss += __shfl_xor(ss, o);
    __syncthreads();
    if ((tid & 63) == 0) sm[tid >> 6] = ss;
    __syncthreads();
    float var = (sm[0] + sm[1] + sm[2] + sm[3]) * (1.f / 768.f);
    float sc = rsqrtf(var + 1e-12f);

    float* y = out + (size_t)row * H_;
    y[tid]       = d0 * sc * g[tid]       + beta[tid];
    y[tid + 256] = d1 * sc * g[tid + 256] + beta[tid + 256];
    y[tid + 512] = d2 * sc * g[tid + 512] + beta[tid + 512];
}

// ---------------------------------------------------------------------------
extern "C" void kernel_launch(void* const* d_in, const int* in_sizes, int n_in,
                              void* d_out, int out_size, void* d_ws, size_t ws_size,
                              hipStream_t stream) {
    const float* hs   = (const float*)d_in[0];
    const float* mask = (const float*)d_in[1];
    const float* Wq   = (const float*)d_in[2];
    const float* bq   = (const float*)d_in[3];
    const float* Wk   = (const float*)d_in[4];
    const float* bk   = (const float*)d_in[5];
    const float* Wv   = (const float*)d_in[6];
    const float* bv   = (const float*)d_in[7];
    const float* Wo   = (const float*)d_in[8];
    const float* bo   = (const float*)d_in[9];
    const float* ln_g = (const float*)d_in[10];
    const float* ln_b = (const float*)d_in[11];
    float* out = (float*)d_out;

    float* w = (float*)d_ws;
    const size_t MH = (size_t)M_ * H_;
    float* qb = w;
    float* kb = w + MH;
    float* vb = w + 2 * MH;
    float* cb = w + 3 * MH;
    float* hb = qb;  // reuse: q dead after attention

    dim3 gg(M_ / 64, H_ / 64);   // 128 x 12
    gemm_bias<false><<<gg, 256, 0, stream>>>(hs, Wq, bq, nullptr, qb, M_, H_, H_);
    gemm_bias<false><<<gg, 256, 0, stream>>>(hs, Wk, bk, nullptr, kb, M_, H_, H_);
    gemm_bias<false><<<gg, 256, 0, stream>>>(hs, Wv, bv, nullptr, vb, M_, H_, H_);

    flash_attn<<<dim3(S_ / 64, NH_, B_), 256, 0, stream>>>(qb, kb, vb, mask, cb);

    gemm_bias<true><<<gg, 256, 0, stream>>>(cb, Wo, bo, hs, hb, M_, H_, H_);

    layernorm_k<<<M_, 256, 0, stream>>>(hb, ln_g, ln_b, out);
}

// Round 3
// 783.991 us; speedup vs baseline: 1.8671x; 1.8671x over previous
//
#include <hip/hip_runtime.h>
#include <math.h>

#define B_  4
#define S_  2048
#define H_  768
#define NH_ 12
#define HD_ 64
#define M_  (B_*S_)   // 8192

using bf16x8 = __attribute__((ext_vector_type(8))) short;
using s16x4  = __attribute__((ext_vector_type(4))) short;
using f32x4  = __attribute__((ext_vector_type(4))) float;

__device__ inline short f2bf(float f) {
    union { float f; unsigned u; } v{f};
    unsigned r = (v.u + 0x7FFF + ((v.u >> 16) & 1)) >> 16;   // RNE
    return (short)r;
}

// ---------------------------------------------------------------------------
// fp32 GEMM (O-proj): C = A @ W^T + bias (+ res). 64x64 tile, BK=16.
// ---------------------------------------------------------------------------
template<bool ADD_RES>
__global__ __launch_bounds__(256)
void gemm_bias(const float* __restrict__ A, const float* __restrict__ W,
               const float* __restrict__ bias, const float* __restrict__ res,
               float* __restrict__ C, int Mdim, int Ndim, int Kdim) {
    __shared__ __align__(16) float As[16][64];
    __shared__ __align__(16) float Ws[16][64];
    const int tid = threadIdx.x;
    const int tx = tid & 15, ty = tid >> 4;
    const int m0 = blockIdx.x * 64, n0 = blockIdx.y * 64;
    const int lr  = tid & 63;
    const int lk4 = (tid >> 6) * 4;

    float acc[4][4] = {};

    for (int k0 = 0; k0 < Kdim; k0 += 16) {
        float4 av = *(const float4*)(A + (size_t)(m0 + lr) * Kdim + k0 + lk4);
        float4 wv = *(const float4*)(W + (size_t)(n0 + lr) * Kdim + k0 + lk4);
        __syncthreads();
        As[lk4+0][lr] = av.x; As[lk4+1][lr] = av.y;
        As[lk4+2][lr] = av.z; As[lk4+3][lr] = av.w;
        Ws[lk4+0][lr] = wv.x; Ws[lk4+1][lr] = wv.y;
        Ws[lk4+2][lr] = wv.z; Ws[lk4+3][lr] = wv.w;
        __syncthreads();
        #pragma unroll
        for (int kk = 0; kk < 16; kk++) {
            float4 a = *(const float4*)&As[kk][ty * 4];
            float4 b = *(const float4*)&Ws[kk][tx * 4];
            acc[0][0] += a.x*b.x; acc[0][1] += a.x*b.y; acc[0][2] += a.x*b.z; acc[0][3] += a.x*b.w;
            acc[1][0] += a.y*b.x; acc[1][1] += a.y*b.y; acc[1][2] += a.y*b.z; acc[1][3] += a.y*b.w;
            acc[2][0] += a.z*b.x; acc[2][1] += a.z*b.y; acc[2][2] += a.z*b.z; acc[2][3] += a.z*b.w;
            acc[3][0] += a.w*b.x; acc[3][1] += a.w*b.y; acc[3][2] += a.w*b.z; acc[3][3] += a.w*b.w;
        }
    }

    const int cn = n0 + tx * 4;
    float4 bv = *(const float4*)(bias + cn);
    #pragma unroll
    for (int i = 0; i < 4; i++) {
        const int cm = m0 + ty * 4 + i;
        float4 o;
        o.x = acc[i][0] + bv.x; o.y = acc[i][1] + bv.y;
        o.z = acc[i][2] + bv.z; o.w = acc[i][3] + bv.w;
        if (ADD_RES) {
            float4 r = *(const float4*)(res + (size_t)cm * Ndim + cn);
            o.x += r.x; o.y += r.y; o.z += r.z; o.w += r.w;
        }
        *(float4*)(C + (size_t)cm * Ndim + cn) = o;
    }
}

// ---------------------------------------------------------------------------
// fp32 GEMM for Q/K/V: epilogue writes bf16 in head-major [b][h][s][d],
// optionally scaled (Q gets 1/sqrt(HD) folded in).
// ---------------------------------------------------------------------------
__global__ __launch_bounds__(256)
void gemm_bias_qkv(const float* __restrict__ A, const float* __restrict__ W,
                   const float* __restrict__ bias, short* __restrict__ obf,
                   float scale) {
    __shared__ __align__(16) float As[16][64];
    __shared__ __align__(16) float Ws[16][64];
    const int tid = threadIdx.x;
    const int tx = tid & 15, ty = tid >> 4;
    const int m0 = blockIdx.x * 64, n0 = blockIdx.y * 64;
    const int lr  = tid & 63;
    const int lk4 = (tid >> 6) * 4;

    float acc[4][4] = {};

    for (int k0 = 0; k0 < H_; k0 += 16) {
        float4 av = *(const float4*)(A + (size_t)(m0 + lr) * H_ + k0 + lk4);
        float4 wv = *(const float4*)(W + (size_t)(n0 + lr) * H_ + k0 + lk4);
        __syncthreads();
        As[lk4+0][lr] = av.x; As[lk4+1][lr] = av.y;
        As[lk4+2][lr] = av.z; As[lk4+3][lr] = av.w;
        Ws[lk4+0][lr] = wv.x; Ws[lk4+1][lr] = wv.y;
        Ws[lk4+2][lr] = wv.z; Ws[lk4+3][lr] = wv.w;
        __syncthreads();
        #pragma unroll
        for (int kk = 0; kk < 16; kk++) {
            float4 a = *(const float4*)&As[kk][ty * 4];
            float4 b = *(const float4*)&Ws[kk][tx * 4];
            acc[0][0] += a.x*b.x; acc[0][1] += a.x*b.y; acc[0][2] += a.x*b.z; acc[0][3] += a.x*b.w;
            acc[1][0] += a.y*b.x; acc[1][1] += a.y*b.y; acc[1][2] += a.y*b.z; acc[1][3] += a.y*b.w;
            acc[2][0] += a.z*b.x; acc[2][1] += a.z*b.y; acc[2][2] += a.z*b.z; acc[2][3] += a.z*b.w;
            acc[3][0] += a.w*b.x; acc[3][1] += a.w*b.y; acc[3][2] += a.w*b.z; acc[3][3] += a.w*b.w;
        }
    }

    const int cn = n0 + tx * 4;
    const int hh = cn >> 6, dd = cn & 63;
    float4 bv = *(const float4*)(bias + cn);
    #pragma unroll
    for (int i = 0; i < 4; i++) {
        const int cm = m0 + ty * 4 + i;
        const int bb = cm >> 11, ss = cm & 2047;
        s16x4 pk;
        pk[0] = f2bf((acc[i][0] + bv.x) * scale);
        pk[1] = f2bf((acc[i][1] + bv.y) * scale);
        pk[2] = f2bf((acc[i][2] + bv.z) * scale);
        pk[3] = f2bf((acc[i][3] + bv.w) * scale);
        *(s16x4*)(obf + (((size_t)(bb * NH_ + hh)) * S_ + ss) * HD_ + dd) = pk;
    }
}

// ---------------------------------------------------------------------------
// MFMA flash attention. Block = 4 waves, Q-tile 64 rows, KV tile 64.
// Wave w owns Q rows [w*16, w*16+16). mfma_f32_16x16x32_bf16.
// A/B frag: lane l reads row (l&15), 8 contiguous k at (l>>4)*8.
// C/D: col = lane&15, row = (lane>>4)*4 + reg.
// ---------------------------------------------------------------------------
__global__ __launch_bounds__(256)
void flash_attn_mfma(const short* __restrict__ q, const short* __restrict__ k,
                     const short* __restrict__ v, const float* __restrict__ mask,
                     float* __restrict__ ctx) {
    const int qt = blockIdx.x, h = blockIdx.y, b = blockIdx.z;
    __shared__ __align__(16) short Ks[64][72];   // K row-major [c][d], pad->2-way
    __shared__ __align__(16) short Vt[64][72];   // V transposed [d][c]
    __shared__ __align__(16) short Ps[64][72];   // P row-major [r][c]
    const int tid = threadIdx.x;
    const int w = tid >> 6, l = tid & 63;
    const int l16 = l & 15, lg = l >> 4;

    // Q A-fragments in registers (already scaled by 0.125 at creation)
    const size_t qbase = (((size_t)(b * NH_ + h)) * S_ + qt * 64 + w * 16 + l16) * HD_ + lg * 8;
    bf16x8 qf0 = *(const bf16x8*)(q + qbase);
    bf16x8 qf1 = *(const bf16x8*)(q + qbase + 32);

    f32x4 oacc[4];
    float m_r[4], l_r[4];
    #pragma unroll
    for (int i = 0; i < 4; i++) {
        m_r[i] = -3.0e38f; l_r[i] = 0.f;
        oacc[i][0] = oacc[i][1] = oacc[i][2] = oacc[i][3] = 0.f;
    }

    for (int ct = 0; ct < S_ / 64; ct++) {
        // ---- stage K (row-major) and V (transposed) ----
        const size_t kvrow0 = ((size_t)(b * NH_ + h)) * S_ + ct * 64;
        bf16x8 gk[2], gv[2];
        int rows[2], offs[2];
        #pragma unroll
        for (int i = 0; i < 2; i++) {
            const int c = tid * 2 + i;          // 0..511 chunks of 8 bf16
            rows[i] = c >> 3; offs[i] = (c & 7) * 8;
            gk[i] = *(const bf16x8*)(k + (kvrow0 + rows[i]) * HD_ + offs[i]);
            gv[i] = *(const bf16x8*)(v + (kvrow0 + rows[i]) * HD_ + offs[i]);
        }
        __syncthreads();   // previous tile's compute done
        #pragma unroll
        for (int i = 0; i < 2; i++) {
            *(bf16x8*)&Ks[rows[i]][offs[i]] = gk[i];
            #pragma unroll
            for (int j = 0; j < 8; j++) Vt[offs[i] + j][rows[i]] = gv[i][j];
        }
        __syncthreads();

        // ---- S = Q K^T (scaled) : 4 col-tiles x 2 k-steps ----
        f32x4 sacc[4];
        #pragma unroll
        for (int n = 0; n < 4; n++) sacc[n][0] = sacc[n][1] = sacc[n][2] = sacc[n][3] = 0.f;
        #pragma unroll
        for (int n = 0; n < 4; n++) {
            bf16x8 kb0 = *(const bf16x8*)&Ks[n * 16 + l16][lg * 8];
            bf16x8 kb1 = *(const bf16x8*)&Ks[n * 16 + l16][32 + lg * 8];
            sacc[n] = __builtin_amdgcn_mfma_f32_16x16x32_bf16(qf0, kb0, sacc[n], 0, 0, 0);
            sacc[n] = __builtin_amdgcn_mfma_f32_16x16x32_bf16(qf1, kb1, sacc[n], 0, 0, 0);
        }

        // ---- additive mask + online softmax ----
        float mk[4];
        #pragma unroll
        for (int n = 0; n < 4; n++) mk[n] = mask[(size_t)b * S_ + ct * 64 + n * 16 + l16];
        #pragma unroll
        for (int n = 0; n < 4; n++)
            #pragma unroll
            for (int r = 0; r < 4; r++) sacc[n][r] += mk[n];

        #pragma unroll
        for (int r = 0; r < 4; r++) {
            float rm = fmaxf(fmaxf(sacc[0][r], sacc[1][r]), fmaxf(sacc[2][r], sacc[3][r]));
            rm = fmaxf(rm, __shfl_xor(rm, 1));
            rm = fmaxf(rm, __shfl_xor(rm, 2));
            rm = fmaxf(rm, __shfl_xor(rm, 4));
            rm = fmaxf(rm, __shfl_xor(rm, 8));
            float mn = fmaxf(m_r[r], rm);
            float corr = __expf(m_r[r] - mn);
            float rs = 0.f;
            #pragma unroll
            for (int n = 0; n < 4; n++) {
                sacc[n][r] = __expf(sacc[n][r] - mn);
                rs += sacc[n][r];
            }
            rs += __shfl_xor(rs, 1);
            rs += __shfl_xor(rs, 2);
            rs += __shfl_xor(rs, 4);
            rs += __shfl_xor(rs, 8);
            l_r[r] = l_r[r] * corr + rs;
            m_r[r] = mn;
            #pragma unroll
            for (int n = 0; n < 4; n++) oacc[n][r] *= corr;
            // write P row (w*16 + lg*4 + r) as bf16
            #pragma unroll
            for (int n = 0; n < 4; n++)
                Ps[w * 16 + lg * 4 + r][n * 16 + l16] = f2bf(sacc[n][r]);
        }

        // ---- O += P V : within-wave LDS round-trip (no barrier needed) ----
        bf16x8 pa0 = *(const bf16x8*)&Ps[w * 16 + l16][lg * 8];
        bf16x8 pa1 = *(const bf16x8*)&Ps[w * 16 + l16][32 + lg * 8];
        #pragma unroll
        for (int nd = 0; nd < 4; nd++) {
            bf16x8 vb0 = *(const bf16x8*)&Vt[nd * 16 + l16][lg * 8];
            bf16x8 vb1 = *(const bf16x8*)&Vt[nd * 16 + l16][32 + lg * 8];
            oacc[nd] = __builtin_amdgcn_mfma_f32_16x16x32_bf16(pa0, vb0, oacc[nd], 0, 0, 0);
            oacc[nd] = __builtin_amdgcn_mfma_f32_16x16x32_bf16(pa1, vb1, oacc[nd], 0, 0, 0);
        }
    }

    // ---- normalize + write ctx fp32 [b][s][H] ----
    #pragma unroll
    for (int r = 0; r < 4; r++) {
        const float inv = 1.f / l_r[r];
        const size_t row = (size_t)(b * S_ + qt * 64 + w * 16 + lg * 4 + r);
        #pragma unroll
        for (int nd = 0; nd < 4; nd++)
            ctx[row * H_ + h * HD_ + nd * 16 + l16] = oacc[nd][r] * inv;
    }
}

// ---------------------------------------------------------------------------
// LayerNorm over last dim (768). One block (256 thr) per row.
// ---------------------------------------------------------------------------
__global__ __launch_bounds__(256)
void layernorm_k(const float* __restrict__ hin, const float* __restrict__ g,
                 const float* __restrict__ beta, float* __restrict__ out) {
    const int row = blockIdx.x;
    const int tid = threadIdx.x;
    const float* x = hin + (size_t)row * H_;
    __shared__ float sm[4];

    float v0 = x[tid], v1 = x[tid + 256], v2 = x[tid + 512];
    float s = v0 + v1 + v2;
    #pragma unroll
    for (int o = 32; o > 0; o >>= 1) s += __shfl_xor(s, o);
    if ((tid & 63) == 0) sm[tid >> 6] = s;
    __syncthreads();
    float mu = (sm[0] + sm[1] + sm[2] + sm[3]) * (1.f / 768.f);

    float d0 = v0 - mu, d1 = v1 - mu, d2 = v2 - mu;
    float ss = d0*d0 + d1*d1 + d2*d2;
    #pragma unroll
    for (int o = 32; o > 0; o >>= 1) ss += __shfl_xor(ss, o);
    __syncthreads();
    if ((tid & 63) == 0) sm[tid >> 6] = ss;
    __syncthreads();
    float var = (sm[0] + sm[1] + sm[2] + sm[3]) * (1.f / 768.f);
    float sc = rsqrtf(var + 1e-12f);

    float* y = out + (size_t)row * H_;
    y[tid]       = d0 * sc * g[tid]       + beta[tid];
    y[tid + 256] = d1 * sc * g[tid + 256] + beta[tid + 256];
    y[tid + 512] = d2 * sc * g[tid + 512] + beta[tid + 512];
}

// ---------------------------------------------------------------------------
extern "C" void kernel_launch(void* const* d_in, const int* in_sizes, int n_in,
                              void* d_out, int out_size, void* d_ws, size_t ws_size,
                              hipStream_t stream) {
    const float* hs   = (const float*)d_in[0];
    const float* mask = (const float*)d_in[1];
    const float* Wq   = (const float*)d_in[2];
    const float* bq   = (const float*)d_in[3];
    const float* Wk   = (const float*)d_in[4];
    const float* bk   = (const float*)d_in[5];
    const float* Wv   = (const float*)d_in[6];
    const float* bv   = (const float*)d_in[7];
    const float* Wo   = (const float*)d_in[8];
    const float* bo   = (const float*)d_in[9];
    const float* ln_g = (const float*)d_in[10];
    const float* ln_b = (const float*)d_in[11];
    float* out = (float*)d_out;

    const size_t MH = (size_t)M_ * H_;
    short* qbf = (short*)d_ws;            // bf16 head-major [b][h][s][d]
    short* kbf = qbf + MH;
    short* vbf = kbf + MH;
    float* cb  = (float*)(vbf + MH);      // ctx fp32 [b][s][H]
    float* hb  = cb + MH;                 // h = ctx@Wo^T + bo + hs

    dim3 gg(M_ / 64, H_ / 64);   // 128 x 12
    gemm_bias_qkv<<<gg, 256, 0, stream>>>(hs, Wq, bq, qbf, 0.125f);
    gemm_bias_qkv<<<gg, 256, 0, stream>>>(hs, Wk, bk, kbf, 1.0f);
    gemm_bias_qkv<<<gg, 256, 0, stream>>>(hs, Wv, bv, vbf, 1.0f);

    flash_attn_mfma<<<dim3(S_ / 64, NH_, B_), 256, 0, stream>>>(qbf, kbf, vbf, mask, cb);

    gemm_bias<true><<<gg, 256, 0, stream>>>(cb, Wo, bo, hs, hb, M_, H_, H_);

    layernorm_k<<<M_, 256, 0, stream>>>(hb, ln_g, ln_b, out);
}

// Round 4
// 305.311 us; speedup vs baseline: 4.7945x; 2.5678x over previous
//
#include <hip/hip_runtime.h>
#include <math.h>

#define B_  4
#define S_  2048
#define H_  768
#define NH_ 12
#define HD_ 64
#define M_  (B_*S_)   // 8192
#define K_  768

using bf16x8 = __attribute__((ext_vector_type(8))) short;
using s16x4  = __attribute__((ext_vector_type(4))) short;
using f32x4  = __attribute__((ext_vector_type(4))) float;

__device__ inline short f2bf(float f) {
    union { float f; unsigned u; } v{f};
    unsigned r = (v.u + 0x7FFF + ((v.u >> 16) & 1)) >> 16;   // RNE
    return (short)r;
}

#define GLDS16(g, l) __builtin_amdgcn_global_load_lds( \
    (const __attribute__((address_space(1))) void*)(g), \
    (__attribute__((address_space(3))) void*)(l), 16, 0, 0)

// ---------------------------------------------------------------------------
// fp32 -> bf16 conversion: region per blockIdx.y (hs, Wq, Wk, Wv, Wo)
// ---------------------------------------------------------------------------
__global__ __launch_bounds__(256)
void cvt5(const float* __restrict__ s0, const float* __restrict__ s1,
          const float* __restrict__ s2, const float* __restrict__ s3,
          const float* __restrict__ s4,
          short* __restrict__ d0, short* __restrict__ d1,
          short* __restrict__ d2, short* __restrict__ d3,
          short* __restrict__ d4) {
    const int r = blockIdx.y;
    const float* s = r == 0 ? s0 : r == 1 ? s1 : r == 2 ? s2 : r == 3 ? s3 : s4;
    short* d      = r == 0 ? d0 : r == 1 ? d1 : r == 2 ? d2 : r == 3 ? d3 : d4;
    const int n4  = (r == 0 ? M_ * H_ : H_ * H_) >> 2;
    for (int i = blockIdx.x * blockDim.x + threadIdx.x; i < n4; i += gridDim.x * blockDim.x) {
        float4 v = ((const float4*)s)[i];
        s16x4 o;
        o[0] = f2bf(v.x); o[1] = f2bf(v.y); o[2] = f2bf(v.z); o[3] = f2bf(v.w);
        ((s16x4*)d)[i] = o;
    }
}

// ---------------------------------------------------------------------------
// bf16 MFMA GEMM: C[m][n] = sum_k A[m][k]*Bw[n][k]  (both K-major, K=768)
// 128x128 tile, BK=32, 4 waves (2x2), 16 MFMA/wave/K-step, global_load_lds.
// MODE 0: out bf16 head-major [b][h][s][d], val=(acc+bias)*scale  (QKV)
// MODE 1: out fp32 [m][768],  val= acc+bias+res                    (O-proj)
// ---------------------------------------------------------------------------
template<int MODE>
__global__ __launch_bounds__(256)
void gemm_bf16(const short* __restrict__ A, const short* __restrict__ Bw,
               const float* __restrict__ bias, const float* __restrict__ res,
               void* __restrict__ out, float scale) {
    __shared__ __align__(16) short As[128 * 32];
    __shared__ __align__(16) short Bs[128 * 32];
    const int tid = threadIdx.x;
    const int w = tid >> 6, l = tid & 63;
    const int l16 = l & 15, lg = l >> 4;
    const int wm = w >> 1, wn = w & 1;
    const int m0 = blockIdx.x * 128, n0 = blockIdx.y * 128;

    f32x4 acc[4][4];
    #pragma unroll
    for (int mi = 0; mi < 4; mi++)
        #pragma unroll
        for (int ni = 0; ni < 4; ni++)
            acc[mi][ni][0] = acc[mi][ni][1] = acc[mi][ni][2] = acc[mi][ni][3] = 0.f;

    // per-lane staging geometry: each wave stages 2KB of each tile in 2 issues
    for (int k0 = 0; k0 < K_; k0 += 32) {
        #pragma unroll
        for (int i = 0; i < 2; i++) {
            const int o = w * 2048 + i * 1024 + l * 16;   // LDS byte offset
            const int row = o >> 6, colb = o & 63;        // 64 B per row (32 bf16)
            const char* ga = (const char*)A  + (((size_t)(m0 + row)) * K_ + k0) * 2 + colb;
            const char* gb = (const char*)Bw + (((size_t)(n0 + row)) * K_ + k0) * 2 + colb;
            GLDS16(ga, (char*)As + w * 2048 + i * 1024);
            GLDS16(gb, (char*)Bs + w * 2048 + i * 1024);
        }
        __syncthreads();   // drains vmcnt: tiles staged

        bf16x8 af[4], bfr[4];
        #pragma unroll
        for (int mi = 0; mi < 4; mi++)
            af[mi] = *(const bf16x8*)&As[(wm * 64 + mi * 16 + l16) * 32 + lg * 8];
        #pragma unroll
        for (int ni = 0; ni < 4; ni++)
            bfr[ni] = *(const bf16x8*)&Bs[(wn * 64 + ni * 16 + l16) * 32 + lg * 8];
        #pragma unroll
        for (int mi = 0; mi < 4; mi++)
            #pragma unroll
            for (int ni = 0; ni < 4; ni++)
                acc[mi][ni] = __builtin_amdgcn_mfma_f32_16x16x32_bf16(af[mi], bfr[ni], acc[mi][ni], 0, 0, 0);
        __syncthreads();   // all waves done reading before next overwrite
    }

    float bcol[4];
    #pragma unroll
    for (int ni = 0; ni < 4; ni++) bcol[ni] = bias[n0 + wn * 64 + ni * 16 + l16];

    if (MODE == 0) {
        short* obf = (short*)out;
        const int h = blockIdx.y * 2 + wn;   // wave's 64-col span == one head
        #pragma unroll
        for (int mi = 0; mi < 4; mi++) {
            #pragma unroll
            for (int r = 0; r < 4; r++) {
                const int row = m0 + wm * 64 + mi * 16 + lg * 4 + r;
                const int bb = row >> 11, ss = row & 2047;
                const size_t base = (((size_t)(bb * NH_ + h)) * S_ + ss) * HD_;
                #pragma unroll
                for (int ni = 0; ni < 4; ni++)
                    obf[base + ni * 16 + l16] = f2bf((acc[mi][ni][r] + bcol[ni]) * scale);
            }
        }
    } else {
        float* o = (float*)out;
        #pragma unroll
        for (int mi = 0; mi < 4; mi++) {
            #pragma unroll
            for (int r = 0; r < 4; r++) {
                const int row = m0 + wm * 64 + mi * 16 + lg * 4 + r;
                #pragma unroll
                for (int ni = 0; ni < 4; ni++) {
                    const int col = n0 + wn * 64 + ni * 16 + l16;
                    o[(size_t)row * H_ + col] = acc[mi][ni][r] + bcol[ni] + res[(size_t)row * H_ + col];
                }
            }
        }
    }
}

// ---------------------------------------------------------------------------
// MFMA flash attention (unchanged structure; ctx out now bf16 [M][H]).
// ---------------------------------------------------------------------------
__global__ __launch_bounds__(256)
void flash_attn_mfma(const short* __restrict__ q, const short* __restrict__ k,
                     const short* __restrict__ v, const float* __restrict__ mask,
                     short* __restrict__ ctx) {
    const int qt = blockIdx.x, h = blockIdx.y, b = blockIdx.z;
    __shared__ __align__(16) short Ks[64][72];
    __shared__ __align__(16) short Vt[64][72];
    __shared__ __align__(16) short Ps[64][72];
    const int tid = threadIdx.x;
    const int w = tid >> 6, l = tid & 63;
    const int l16 = l & 15, lg = l >> 4;

    const size_t qbase = (((size_t)(b * NH_ + h)) * S_ + qt * 64 + w * 16 + l16) * HD_ + lg * 8;
    bf16x8 qf0 = *(const bf16x8*)(q + qbase);
    bf16x8 qf1 = *(const bf16x8*)(q + qbase + 32);

    f32x4 oacc[4];
    float m_r[4], l_r[4];
    #pragma unroll
    for (int i = 0; i < 4; i++) {
        m_r[i] = -3.0e38f; l_r[i] = 0.f;
        oacc[i][0] = oacc[i][1] = oacc[i][2] = oacc[i][3] = 0.f;
    }

    for (int ct = 0; ct < S_ / 64; ct++) {
        const size_t kvrow0 = ((size_t)(b * NH_ + h)) * S_ + ct * 64;
        bf16x8 gk[2], gv[2];
        int rows[2], offs[2];
        #pragma unroll
        for (int i = 0; i < 2; i++) {
            const int c = tid * 2 + i;
            rows[i] = c >> 3; offs[i] = (c & 7) * 8;
            gk[i] = *(const bf16x8*)(k + (kvrow0 + rows[i]) * HD_ + offs[i]);
            gv[i] = *(const bf16x8*)(v + (kvrow0 + rows[i]) * HD_ + offs[i]);
        }
        __syncthreads();
        #pragma unroll
        for (int i = 0; i < 2; i++) {
            *(bf16x8*)&Ks[rows[i]][offs[i]] = gk[i];
            #pragma unroll
            for (int j = 0; j < 8; j++) Vt[offs[i] + j][rows[i]] = gv[i][j];
        }
        __syncthreads();

        f32x4 sacc[4];
        #pragma unroll
        for (int n = 0; n < 4; n++) sacc[n][0] = sacc[n][1] = sacc[n][2] = sacc[n][3] = 0.f;
        #pragma unroll
        for (int n = 0; n < 4; n++) {
            bf16x8 kb0 = *(const bf16x8*)&Ks[n * 16 + l16][lg * 8];
            bf16x8 kb1 = *(const bf16x8*)&Ks[n * 16 + l16][32 + lg * 8];
            sacc[n] = __builtin_amdgcn_mfma_f32_16x16x32_bf16(qf0, kb0, sacc[n], 0, 0, 0);
            sacc[n] = __builtin_amdgcn_mfma_f32_16x16x32_bf16(qf1, kb1, sacc[n], 0, 0, 0);
        }

        float mk[4];
        #pragma unroll
        for (int n = 0; n < 4; n++) mk[n] = mask[(size_t)b * S_ + ct * 64 + n * 16 + l16];
        #pragma unroll
        for (int n = 0; n < 4; n++)
            #pragma unroll
            for (int r = 0; r < 4; r++) sacc[n][r] += mk[n];

        #pragma unroll
        for (int r = 0; r < 4; r++) {
            float rm = fmaxf(fmaxf(sacc[0][r], sacc[1][r]), fmaxf(sacc[2][r], sacc[3][r]));
            rm = fmaxf(rm, __shfl_xor(rm, 1));
            rm = fmaxf(rm, __shfl_xor(rm, 2));
            rm = fmaxf(rm, __shfl_xor(rm, 4));
            rm = fmaxf(rm, __shfl_xor(rm, 8));
            float mn = fmaxf(m_r[r], rm);
            float corr = __expf(m_r[r] - mn);
            float rs = 0.f;
            #pragma unroll
            for (int n = 0; n < 4; n++) {
                sacc[n][r] = __expf(sacc[n][r] - mn);
                rs += sacc[n][r];
            }
            rs += __shfl_xor(rs, 1);
            rs += __shfl_xor(rs, 2);
            rs += __shfl_xor(rs, 4);
            rs += __shfl_xor(rs, 8);
            l_r[r] = l_r[r] * corr + rs;
            m_r[r] = mn;
            #pragma unroll
            for (int n = 0; n < 4; n++) oacc[n][r] *= corr;
            #pragma unroll
            for (int n = 0; n < 4; n++)
                Ps[w * 16 + lg * 4 + r][n * 16 + l16] = f2bf(sacc[n][r]);
        }

        bf16x8 pa0 = *(const bf16x8*)&Ps[w * 16 + l16][lg * 8];
        bf16x8 pa1 = *(const bf16x8*)&Ps[w * 16 + l16][32 + lg * 8];
        #pragma unroll
        for (int nd = 0; nd < 4; nd++) {
            bf16x8 vb0 = *(const bf16x8*)&Vt[nd * 16 + l16][lg * 8];
            bf16x8 vb1 = *(const bf16x8*)&Vt[nd * 16 + l16][32 + lg * 8];
            oacc[nd] = __builtin_amdgcn_mfma_f32_16x16x32_bf16(pa0, vb0, oacc[nd], 0, 0, 0);
            oacc[nd] = __builtin_amdgcn_mfma_f32_16x16x32_bf16(pa1, vb1, oacc[nd], 0, 0, 0);
        }
    }

    #pragma unroll
    for (int r = 0; r < 4; r++) {
        const float inv = 1.f / l_r[r];
        const size_t row = (size_t)(b * S_ + qt * 64 + w * 16 + lg * 4 + r);
        #pragma unroll
        for (int nd = 0; nd < 4; nd++)
            ctx[row * H_ + h * HD_ + nd * 16 + l16] = f2bf(oacc[nd][r] * inv);
    }
}

// ---------------------------------------------------------------------------
// LayerNorm over last dim (768). One block (256 thr) per row.
// ---------------------------------------------------------------------------
__global__ __launch_bounds__(256)
void layernorm_k(const float* __restrict__ hin, const float* __restrict__ g,
                 const float* __restrict__ beta, float* __restrict__ out) {
    const int row = blockIdx.x;
    const int tid = threadIdx.x;
    const float* x = hin + (size_t)row * H_;
    __shared__ float sm[4];

    float v0 = x[tid], v1 = x[tid + 256], v2 = x[tid + 512];
    float s = v0 + v1 + v2;
    #pragma unroll
    for (int o = 32; o > 0; o >>= 1) s += __shfl_xor(s, o);
    if ((tid & 63) == 0) sm[tid >> 6] = s;
    __syncthreads();
    float mu = (sm[0] + sm[1] + sm[2] + sm[3]) * (1.f / 768.f);

    float d0 = v0 - mu, d1 = v1 - mu, d2 = v2 - mu;
    float ss = d0*d0 + d1*d1 + d2*d2;
    #pragma unroll
    for (int o = 32; o > 0; o >>= 1) ss += __shfl_xor(ss, o);
    __syncthreads();
    if ((tid & 63) == 0) sm[tid >> 6] = ss;
    __syncthreads();
    float var = (sm[0] + sm[1] + sm[2] + sm[3]) * (1.f / 768.f);
    float sc = rsqrtf(var + 1e-12f);

    float* y = out + (size_t)row * H_;
    y[tid]       = d0 * sc * g[tid]       + beta[tid];
    y[tid + 256] = d1 * sc * g[tid + 256] + beta[tid + 256];
    y[tid + 512] = d2 * sc * g[tid + 512] + beta[tid + 512];
}

// ---------------------------------------------------------------------------
extern "C" void kernel_launch(void* const* d_in, const int* in_sizes, int n_in,
                              void* d_out, int out_size, void* d_ws, size_t ws_size,
                              hipStream_t stream) {
    const float* hs   = (const float*)d_in[0];
    const float* mask = (const float*)d_in[1];
    const float* Wq   = (const float*)d_in[2];
    const float* bq   = (const float*)d_in[3];
    const float* Wk   = (const float*)d_in[4];
    const float* bk   = (const float*)d_in[5];
    const float* Wv   = (const float*)d_in[6];
    const float* bv   = (const float*)d_in[7];
    const float* Wo   = (const float*)d_in[8];
    const float* bo   = (const float*)d_in[9];
    const float* ln_g = (const float*)d_in[10];
    const float* ln_b = (const float*)d_in[11];
    float* out = (float*)d_out;

    const size_t MH = (size_t)M_ * H_;
    const size_t HH = (size_t)H_ * H_;
    short* hsbf = (short*)d_ws;       // [M][768] bf16
    short* wqbf = hsbf + MH;          // [768][768] bf16
    short* wkbf = wqbf + HH;
    short* wvbf = wkbf + HH;
    short* wobf = wvbf + HH;
    short* qbf  = wobf + HH;          // head-major [b][h][s][d] bf16
    short* kbf  = qbf + MH;
    short* vbf  = kbf + MH;
    short* cbf  = vbf + MH;           // ctx bf16 [M][768]
    float* hb   = (float*)(cbf + MH); // fp32 [M][768]

    cvt5<<<dim3(256, 5), 256, 0, stream>>>(hs, Wq, Wk, Wv, Wo,
                                           hsbf, wqbf, wkbf, wvbf, wobf);

    dim3 gg(M_ / 128, H_ / 128);   // 64 x 6
    gemm_bf16<0><<<gg, 256, 0, stream>>>(hsbf, wqbf, bq, nullptr, qbf, 0.125f);
    gemm_bf16<0><<<gg, 256, 0, stream>>>(hsbf, wkbf, bk, nullptr, kbf, 1.0f);
    gemm_bf16<0><<<gg, 256, 0, stream>>>(hsbf, wvbf, bv, nullptr, vbf, 1.0f);

    flash_attn_mfma<<<dim3(S_ / 64, NH_, B_), 256, 0, stream>>>(qbf, kbf, vbf, mask, cbf);

    gemm_bf16<1><<<gg, 256, 0, stream>>>(cbf, wobf, bo, hs, hb, 1.0f);

    layernorm_k<<<M_, 256, 0, stream>>>(hb, ln_g, ln_b, out);
}

// Round 5
// 225.828 us; speedup vs baseline: 6.4820x; 1.3520x over previous
//
#include <hip/hip_runtime.h>
#include <math.h>

#define B_  4
#define S_  2048
#define H_  768
#define NH_ 12
#define HD_ 64
#define M_  (B_*S_)   // 8192
#define K_  768

using bf16x8 = __attribute__((ext_vector_type(8))) short;
using s16x4  = __attribute__((ext_vector_type(4))) short;
using f32x4  = __attribute__((ext_vector_type(4))) float;

__device__ inline short f2bf(float f) {
    union { float f; unsigned u; } v{f};
    unsigned r = (v.u + 0x7FFF + ((v.u >> 16) & 1)) >> 16;   // RNE
    return (short)r;
}

#define GLDS16(g, l) __builtin_amdgcn_global_load_lds( \
    (const __attribute__((address_space(1))) void*)(g), \
    (__attribute__((address_space(3))) void*)(l), 16, 0, 0)

// swizzled LDS read: linear [64][128B] tile, byte ^= ((row&7)<<4)
__device__ inline const bf16x8* LDSRD(const short* base, int row, int colByte) {
    return (const bf16x8*)((const char*)base + ((row << 7) + (colByte ^ ((row & 7) << 4))));
}

// ---------------------------------------------------------------------------
// fp32 -> bf16 conversion: region per blockIdx.y (hs, Wq, Wk, Wv, Wo)
// ---------------------------------------------------------------------------
__global__ __launch_bounds__(256)
void cvt5(const float* __restrict__ s0, const float* __restrict__ s1,
          const float* __restrict__ s2, const float* __restrict__ s3,
          const float* __restrict__ s4,
          short* __restrict__ d0, short* __restrict__ d1,
          short* __restrict__ d2, short* __restrict__ d3,
          short* __restrict__ d4) {
    const int r = blockIdx.y;
    const float* s = r == 0 ? s0 : r == 1 ? s1 : r == 2 ? s2 : r == 3 ? s3 : s4;
    short* d      = r == 0 ? d0 : r == 1 ? d1 : r == 2 ? d2 : r == 3 ? d3 : d4;
    const int n4  = (r == 0 ? M_ * H_ : H_ * H_) >> 2;
    for (int i = blockIdx.x * blockDim.x + threadIdx.x; i < n4; i += gridDim.x * blockDim.x) {
        float4 v = ((const float4*)s)[i];
        s16x4 o;
        o[0] = f2bf(v.x); o[1] = f2bf(v.y); o[2] = f2bf(v.z); o[3] = f2bf(v.w);
        ((s16x4*)d)[i] = o;
    }
}

// ---------------------------------------------------------------------------
// bf16 MFMA GEMM (m97 structure): 128x128 tile, BK=32, global_load_lds.
// MODE 0: out bf16 head-major [b][h][s][d], val=(acc+bias)*scale  (QKV)
// MODE 1: out fp32 [m][768],  val= acc+bias+res                    (O-proj)
// ---------------------------------------------------------------------------
template<int MODE>
__global__ __launch_bounds__(256)
void gemm_bf16(const short* __restrict__ A, const short* __restrict__ Bw,
               const float* __restrict__ bias, const float* __restrict__ res,
               void* __restrict__ out, float scale) {
    __shared__ __align__(16) short As[128 * 32];
    __shared__ __align__(16) short Bs[128 * 32];
    const int tid = threadIdx.x;
    const int w = tid >> 6, l = tid & 63;
    const int l16 = l & 15, lg = l >> 4;
    const int wm = w >> 1, wn = w & 1;
    const int m0 = blockIdx.x * 128, n0 = blockIdx.y * 128;

    f32x4 acc[4][4];
    #pragma unroll
    for (int mi = 0; mi < 4; mi++)
        #pragma unroll
        for (int ni = 0; ni < 4; ni++)
            acc[mi][ni][0] = acc[mi][ni][1] = acc[mi][ni][2] = acc[mi][ni][3] = 0.f;

    for (int k0 = 0; k0 < K_; k0 += 32) {
        #pragma unroll
        for (int i = 0; i < 2; i++) {
            const int o = w * 2048 + i * 1024 + l * 16;
            const int row = o >> 6, colb = o & 63;
            const char* ga = (const char*)A  + (((size_t)(m0 + row)) * K_ + k0) * 2 + colb;
            const char* gb = (const char*)Bw + (((size_t)(n0 + row)) * K_ + k0) * 2 + colb;
            GLDS16(ga, (char*)As + w * 2048 + i * 1024);
            GLDS16(gb, (char*)Bs + w * 2048 + i * 1024);
        }
        __syncthreads();

        bf16x8 af[4], bfr[4];
        #pragma unroll
        for (int mi = 0; mi < 4; mi++)
            af[mi] = *(const bf16x8*)&As[(wm * 64 + mi * 16 + l16) * 32 + lg * 8];
        #pragma unroll
        for (int ni = 0; ni < 4; ni++)
            bfr[ni] = *(const bf16x8*)&Bs[(wn * 64 + ni * 16 + l16) * 32 + lg * 8];
        #pragma unroll
        for (int mi = 0; mi < 4; mi++)
            #pragma unroll
            for (int ni = 0; ni < 4; ni++)
                acc[mi][ni] = __builtin_amdgcn_mfma_f32_16x16x32_bf16(af[mi], bfr[ni], acc[mi][ni], 0, 0, 0);
        __syncthreads();
    }

    float bcol[4];
    #pragma unroll
    for (int ni = 0; ni < 4; ni++) bcol[ni] = bias[n0 + wn * 64 + ni * 16 + l16];

    if (MODE == 0) {
        short* obf = (short*)out;
        const int h = blockIdx.y * 2 + wn;
        #pragma unroll
        for (int mi = 0; mi < 4; mi++) {
            #pragma unroll
            for (int r = 0; r < 4; r++) {
                const int row = m0 + wm * 64 + mi * 16 + lg * 4 + r;
                const int bb = row >> 11, ss = row & 2047;
                const size_t base = (((size_t)(bb * NH_ + h)) * S_ + ss) * HD_;
                #pragma unroll
                for (int ni = 0; ni < 4; ni++)
                    obf[base + ni * 16 + l16] = f2bf((acc[mi][ni][r] + bcol[ni]) * scale);
            }
        }
    } else {
        float* o = (float*)out;
        #pragma unroll
        for (int mi = 0; mi < 4; mi++) {
            #pragma unroll
            for (int r = 0; r < 4; r++) {
                const int row = m0 + wm * 64 + mi * 16 + lg * 4 + r;
                #pragma unroll
                for (int ni = 0; ni < 4; ni++) {
                    const int col = n0 + wn * 64 + ni * 16 + l16;
                    o[(size_t)row * H_ + col] = acc[mi][ni][r] + bcol[ni] + res[(size_t)row * H_ + col];
                }
            }
        }
    }
}

// ---------------------------------------------------------------------------
// V transpose: [b][h][s][d] -> [b][h][d][s].  64x64 LDS tiles, XOR-swizzled.
// ---------------------------------------------------------------------------
__global__ __launch_bounds__(256)
void transpose_v(const short* __restrict__ vin, short* __restrict__ vout) {
    __shared__ __align__(16) short L[4096];
    const int bh = blockIdx.y, st = blockIdx.x * 64;
    const int t = threadIdx.x;
    const int sl = t >> 2, d0 = (t & 3) * 16;
    const short* g = vin + ((size_t)bh * S_ + st + sl) * HD_ + d0;
    #pragma unroll
    for (int u = 0; u < 2; u++) {
        const int cb = (d0 + u * 8) * 2;
        *(bf16x8*)((char*)L + (sl << 7) + (cb ^ ((sl & 7) << 4))) = *(const bf16x8*)(g + u * 8);
    }
    __syncthreads();
    const int d = t >> 2, s0 = (t & 3) * 16;
    short tmp[16];
    #pragma unroll
    for (int j = 0; j < 16; j++) {
        const int row = s0 + j;
        tmp[j] = *(const short*)((const char*)L + (row << 7) + ((d * 2) ^ ((row & 7) << 4)));
    }
    short* o = vout + ((size_t)bh * HD_ + d) * S_ + st + s0;
    *(bf16x8*)(o)     = *(bf16x8*)&tmp[0];
    *(bf16x8*)(o + 8) = *(bf16x8*)&tmp[8];
}

// ---------------------------------------------------------------------------
// MFMA flash attention, swapped-QK^T structure.
// Block = 4 waves; wave w owns q rows [w*16, w*16+16).  KV tile 64.
// QK^T: mfma(K,Q) -> lane holds S[kc=16n+4lg+r][qr=l16] -> lane-local softmax.
// PV:   P staged to LDS (vector b64), A=P rows, B=Vt rows (global-transposed V).
// All LDS tiles linear [64][128B] with byte^((row&7)<<4) swizzle (T2/m214).
// ---------------------------------------------------------------------------
__global__ __launch_bounds__(256)
void flash_attn_mfma(const short* __restrict__ q, const short* __restrict__ k,
                     const short* __restrict__ vt, const float* __restrict__ mask,
                     short* __restrict__ ctx) {
    const int qt = blockIdx.x, h = blockIdx.y, b = blockIdx.z;
    __shared__ __align__(16) short KsL[4096];
    __shared__ __align__(16) short VtL[4096];
    __shared__ __align__(16) short PsL[4096];
    const int tid = threadIdx.x;
    const int w = tid >> 6, l = tid & 63;
    const int l16 = l & 15, lg = l >> 4;

    // Q fragments (B operand): row = q-row w*16+l16, k = d
    const size_t qrow = ((size_t)(b * NH_ + h)) * S_ + qt * 64 + w * 16 + l16;
    bf16x8 qf0 = *(const bf16x8*)(q + qrow * HD_ + lg * 8);
    bf16x8 qf1 = *(const bf16x8*)(q + qrow * HD_ + 32 + lg * 8);

    const size_t kbase  = ((size_t)(b * NH_ + h)) * S_ * HD_;   // K  [s][d]
    const size_t vtbase = ((size_t)(b * NH_ + h)) * HD_ * S_;   // Vt [d][s]

    f32x4 oacc[4];
    #pragma unroll
    for (int i = 0; i < 4; i++) oacc[i][0] = oacc[i][1] = oacc[i][2] = oacc[i][3] = 0.f;
    float m_reg = -3.0e38f, l_reg = 0.f;

    for (int ct = 0; ct < S_ / 64; ct++) {
        // ---- stage K and Vt tiles: global_load_lds, pre-swizzled source ----
        #pragma unroll
        for (int i = 0; i < 2; i++) {
            const int o = (w * 2 + i) * 1024 + l * 16;
            const int row = o >> 7;
            const int cb = (o & 127) ^ ((row & 7) << 4);
            const char* gk = (const char*)(k  + kbase  + (size_t)(ct * 64 + row) * HD_) + cb;
            const char* gv = (const char*)(vt + vtbase + (size_t)row * S_ + ct * 64) + cb;
            GLDS16(gk, (char*)KsL + o);
            GLDS16(gv, (char*)VtL + o);
        }
        __syncthreads();   // vmcnt drained: tiles ready

        // ---- S^T = mfma(K, Q): lane holds 16 vals of q-row (w*16+l16) ----
        f32x4 sacc[4];
        #pragma unroll
        for (int n = 0; n < 4; n++) {
            sacc[n][0] = sacc[n][1] = sacc[n][2] = sacc[n][3] = 0.f;
            bf16x8 kb0 = *LDSRD(KsL, n * 16 + l16, lg * 16);
            bf16x8 kb1 = *LDSRD(KsL, n * 16 + l16, 64 + lg * 16);
            sacc[n] = __builtin_amdgcn_mfma_f32_16x16x32_bf16(kb0, qf0, sacc[n], 0, 0, 0);
            sacc[n] = __builtin_amdgcn_mfma_f32_16x16x32_bf16(kb1, qf1, sacc[n], 0, 0, 0);
        }

        // ---- mask (per kc = 16n+4lg+r) ----
        #pragma unroll
        for (int n = 0; n < 4; n++) {
            float4 mk = *(const float4*)(mask + (size_t)b * S_ + ct * 64 + n * 16 + lg * 4);
            sacc[n][0] += mk.x; sacc[n][1] += mk.y; sacc[n][2] += mk.z; sacc[n][3] += mk.w;
        }

        // ---- lane-local online softmax for q-row l16 ----
        float pmax = sacc[0][0];
        #pragma unroll
        for (int n = 0; n < 4; n++)
            #pragma unroll
            for (int r = 0; r < 4; r++) pmax = fmaxf(pmax, sacc[n][r]);
        pmax = fmaxf(pmax, __shfl_xor(pmax, 16));
        pmax = fmaxf(pmax, __shfl_xor(pmax, 32));
        const float mn = fmaxf(m_reg, pmax);
        const float corr = __expf(m_reg - mn);
        float rs = 0.f;
        #pragma unroll
        for (int n = 0; n < 4; n++)
            #pragma unroll
            for (int r = 0; r < 4; r++) {
                sacc[n][r] = __expf(sacc[n][r] - mn);
                rs += sacc[n][r];
            }
        rs += __shfl_xor(rs, 16);
        rs += __shfl_xor(rs, 32);
        l_reg = l_reg * corr + rs;
        m_reg = mn;

        // ---- P -> LDS (vector b64 per n), row = q-row, col = kc ----
        const int prow = w * 16 + l16;
        #pragma unroll
        for (int n = 0; n < 4; n++) {
            s16x4 pk;
            pk[0] = f2bf(sacc[n][0]); pk[1] = f2bf(sacc[n][1]);
            pk[2] = f2bf(sacc[n][2]); pk[3] = f2bf(sacc[n][3]);
            *(s16x4*)((char*)PsL + (prow << 7) + ((32 * n + 8 * lg) ^ ((prow & 7) << 4))) = pk;
        }

        // ---- rescale O (O rows are lg*4+r) ----
        float corr4[4];
        #pragma unroll
        for (int r = 0; r < 4; r++) corr4[r] = __shfl(corr, lg * 4 + r);
        #pragma unroll
        for (int nd = 0; nd < 4; nd++)
            #pragma unroll
            for (int r = 0; r < 4; r++) oacc[nd][r] *= corr4[r];

        // ---- O += P V ----
        bf16x8 pa0 = *LDSRD(PsL, prow, lg * 16);
        bf16x8 pa1 = *LDSRD(PsL, prow, 64 + lg * 16);
        #pragma unroll
        for (int nd = 0; nd < 4; nd++) {
            bf16x8 vb0 = *LDSRD(VtL, nd * 16 + l16, lg * 16);
            bf16x8 vb1 = *LDSRD(VtL, nd * 16 + l16, 64 + lg * 16);
            oacc[nd] = __builtin_amdgcn_mfma_f32_16x16x32_bf16(pa0, vb0, oacc[nd], 0, 0, 0);
            oacc[nd] = __builtin_amdgcn_mfma_f32_16x16x32_bf16(pa1, vb1, oacc[nd], 0, 0, 0);
        }
        __syncthreads();   // done reading KsL/VtL before next stage
    }

    // ---- normalize + write ctx bf16 [M][H] ----
    #pragma unroll
    for (int r = 0; r < 4; r++) {
        const float inv = 1.f / __shfl(l_reg, lg * 4 + r);
        const size_t row = (size_t)(b * S_ + qt * 64 + w * 16 + lg * 4 + r);
        #pragma unroll
        for (int nd = 0; nd < 4; nd++)
            ctx[row * H_ + h * HD_ + nd * 16 + l16] = f2bf(oacc[nd][r] * inv);
    }
}

// ---------------------------------------------------------------------------
// LayerNorm over last dim (768). One block (256 thr) per row.
// ---------------------------------------------------------------------------
__global__ __launch_bounds__(256)
void layernorm_k(const float* __restrict__ hin, const float* __restrict__ g,
                 const float* __restrict__ beta, float* __restrict__ out) {
    const int row = blockIdx.x;
    const int tid = threadIdx.x;
    const float* x = hin + (size_t)row * H_;
    __shared__ float sm[4];

    float v0 = x[tid], v1 = x[tid + 256], v2 = x[tid + 512];
    float s = v0 + v1 + v2;
    #pragma unroll
    for (int o = 32; o > 0; o >>= 1) s += __shfl_xor(s, o);
    if ((tid & 63) == 0) sm[tid >> 6] = s;
    __syncthreads();
    float mu = (sm[0] + sm[1] + sm[2] + sm[3]) * (1.f / 768.f);

    float d0 = v0 - mu, d1 = v1 - mu, d2 = v2 - mu;
    float ss = d0*d0 + d1*d1 + d2*d2;
    #pragma unroll
    for (int o = 32; o > 0; o >>= 1) ss += __shfl_xor(ss, o);
    __syncthreads();
    if ((tid & 63) == 0) sm[tid >> 6] = ss;
    __syncthreads();
    float var = (sm[0] + sm[1] + sm[2] + sm[3]) * (1.f / 768.f);
    float sc = rsqrtf(var + 1e-12f);

    float* y = out + (size_t)row * H_;
    y[tid]       = d0 * sc * g[tid]       + beta[tid];
    y[tid + 256] = d1 * sc * g[tid + 256] + beta[tid + 256];
    y[tid + 512] = d2 * sc * g[tid + 512] + beta[tid + 512];
}

// ---------------------------------------------------------------------------
extern "C" void kernel_launch(void* const* d_in, const int* in_sizes, int n_in,
                              void* d_out, int out_size, void* d_ws, size_t ws_size,
                              hipStream_t stream) {
    const float* hs   = (const float*)d_in[0];
    const float* mask = (const float*)d_in[1];
    const float* Wq   = (const float*)d_in[2];
    const float* bq   = (const float*)d_in[3];
    const float* Wk   = (const float*)d_in[4];
    const float* bk   = (const float*)d_in[5];
    const float* Wv   = (const float*)d_in[6];
    const float* bv   = (const float*)d_in[7];
    const float* Wo   = (const float*)d_in[8];
    const float* bo   = (const float*)d_in[9];
    const float* ln_g = (const float*)d_in[10];
    const float* ln_b = (const float*)d_in[11];
    float* out = (float*)d_out;

    const size_t MH = (size_t)M_ * H_;
    const size_t HH = (size_t)H_ * H_;
    short* hsbf = (short*)d_ws;       // [M][768] bf16
    short* wqbf = hsbf + MH;
    short* wkbf = wqbf + HH;
    short* wvbf = wkbf + HH;
    short* wobf = wvbf + HH;
    short* qbf  = wobf + HH;          // [b][h][s][d]
    short* kbf  = qbf + MH;
    short* vbf  = kbf + MH;           // [b][h][s][d]
    short* vtb  = vbf + MH;           // [b][h][d][s]
    short* cbf  = vtb + MH;           // ctx bf16 [M][768]
    float* hb   = (float*)(cbf + MH); // fp32 [M][768]

    cvt5<<<dim3(256, 5), 256, 0, stream>>>(hs, Wq, Wk, Wv, Wo,
                                           hsbf, wqbf, wkbf, wvbf, wobf);

    dim3 gg(M_ / 128, H_ / 128);   // 64 x 6
    gemm_bf16<0><<<gg, 256, 0, stream>>>(hsbf, wqbf, bq, nullptr, qbf, 0.125f);
    gemm_bf16<0><<<gg, 256, 0, stream>>>(hsbf, wkbf, bk, nullptr, kbf, 1.0f);
    gemm_bf16<0><<<gg, 256, 0, stream>>>(hsbf, wvbf, bv, nullptr, vbf, 1.0f);

    transpose_v<<<dim3(S_ / 64, B_ * NH_), 256, 0, stream>>>(vbf, vtb);

    flash_attn_mfma<<<dim3(S_ / 64, NH_, B_), 256, 0, stream>>>(qbf, kbf, vtb, mask, cbf);

    gemm_bf16<1><<<gg, 256, 0, stream>>>(cbf, wobf, bo, hs, hb, 1.0f);

    layernorm_k<<<M_, 256, 0, stream>>>(hb, ln_g, ln_b, out);
}